// Round 2
// baseline (839.878 us; speedup 1.0000x reference)
//
#include <hip/hip_runtime.h>
#include <cstdint>

typedef unsigned short u16;
typedef __attribute__((ext_vector_type(8))) short short8;
typedef __attribute__((ext_vector_type(4))) float floatx4;

#define NQP   64
#define MQP   128
#define NP    2080
#define NHH   8192
#define NOUT  10464   /* 2080 + 64 + 8192 + 128 */
#define NOUTP 10496   /* padded to 82*128 */

__device__ __forceinline__ float b2f(u16 u) {
  union { unsigned int i; float f; } v; v.i = ((unsigned int)u) << 16; return v.f;
}
__device__ __forceinline__ u16 f2b(float f) {
  union { float f; unsigned int i; } v; v.f = f;
  unsigned int r = v.i + 0x7fffu + ((v.i >> 16) & 1u);
  return (u16)(r >> 16);
}

// ---------------------------------------------------------------------------
// dtype detector: true-bf16 u16 words have exponent field ~[110,126];
// f32-mantissa words are ~uniform. flag=1 -> inputs are f32.
// ---------------------------------------------------------------------------
__global__ __launch_bounds__(256) void detect_dtype(const u16* __restrict__ w,
                                                    int* __restrict__ flag) {
  __shared__ int cnt;
  if (threadIdx.x == 0) cnt = 0;
  __syncthreads();
  int c = 0;
  for (int i = threadIdx.x; i < 16384; i += 256) {
    const int e = (w[i] >> 7) & 0xFF;
    if (e >= 130 || e <= 90) ++c;
  }
  atomicAdd(&cnt, c);
  __syncthreads();
  if (threadIdx.x == 0) flag[0] = (cnt > 3000) ? 1 : 0;
}

__device__ __forceinline__ u16 load_elem_bf16(const void* p, size_t idx, int isf32) {
  return isf32 ? f2b(((const float*)p)[idx]) : ((const u16*)p)[idx];
}

// element-wise dtype normalize to bf16
__global__ __launch_bounds__(256) void convert_bf16(const void* __restrict__ in,
                                                    u16* __restrict__ out, int n,
                                                    const int* __restrict__ flag) {
  const int isf = flag[0];
  for (int i = blockIdx.x * 256 + threadIdx.x; i < n; i += gridDim.x * 256)
    out[i] = load_elem_bf16(in, i, isf);
}

// bias -> f32
__global__ __launch_bounds__(256) void convert_f32(const void* __restrict__ in,
                                                   float* __restrict__ out, int n,
                                                   const int* __restrict__ flag) {
  const int isf = flag[0];
  for (int i = blockIdx.x * 256 + threadIdx.x; i < n; i += gridDim.x * 256)
    out[i] = isf ? ((const float*)in)[i] : b2f(((const u16*)in)[i]);
}

// ---------------------------------------------------------------------------
// Transpose (+ zero-pad rows): in = K x N row-major (f32 or bf16 per flag)
// out = Npad x K row-major bf16 (out[n][k] = in[k][n], 0 for n>=N)
// ---------------------------------------------------------------------------
__global__ __launch_bounds__(256) void transpose_pad(const void* __restrict__ in,
                                                     u16* __restrict__ out,
                                                     int K, int N, int Npad,
                                                     const int* __restrict__ flag) {
  __shared__ u16 tile[32][33];
  const int isf = flag[0];
  const int n0 = blockIdx.x * 32, k0 = blockIdx.y * 32;
  const int tx = threadIdx.x & 31, ty = threadIdx.x >> 5;
#pragma unroll
  for (int i = 0; i < 4; ++i) {
    const int k = k0 + ty + 8 * i, n = n0 + tx;
    tile[ty + 8 * i][tx] = (n < N) ? load_elem_bf16(in, (size_t)k * N + n, isf) : (u16)0;
  }
  __syncthreads();
#pragma unroll
  for (int i = 0; i < 4; ++i) {
    const int n = n0 + ty + 8 * i, k = k0 + tx;
    if (n < Npad) out[(size_t)n * K + k] = tile[tx][ty + 8 * i];
  }
}

// ---------------------------------------------------------------------------
// GEMM: C[M,N] = (Ahi + Alo)[M,K] @ Bt[N,K]^T + bias, m97-style 128x128 tile.
// EPI==0: relu then split-store bf16 hi/lo.  EPI==1: store f32.
// ---------------------------------------------------------------------------
__device__ __forceinline__ void gload_lds16(const u16* g, u16* l) {
  __builtin_amdgcn_global_load_lds((const __attribute__((address_space(1))) void*)g,
                                   (__attribute__((address_space(3))) void*)l, 16, 0, 0);
}

template <int EPI, bool HAS_LO>
__global__ __launch_bounds__(256) void gemm_bt(const u16* __restrict__ Ahi, const u16* __restrict__ Alo,
                                               const u16* __restrict__ Bt,  const float* __restrict__ bias,
                                               u16* __restrict__ Chi, u16* __restrict__ Clo,
                                               float* __restrict__ Cf,
                                               int M, int N, int K) {
  __shared__ __align__(16) u16 lA[128 * 32];
  __shared__ __align__(16) u16 lAlo[128 * 32];
  __shared__ __align__(16) u16 lB[128 * 32];
  const int tile_n = blockIdx.x * 128;
  const int tile_m = blockIdx.y * 128;
  const int lane = threadIdx.x & 63;
  const int wv   = threadIdx.x >> 6;
  const int wm = (wv & 1) * 64;
  const int wn = (wv >> 1) * 64;
  const int sr = lane >> 2;        // staging: row within 16-row group
  const int sk = (lane & 3) * 8;   // staging: k element offset (16B)
  floatx4 acc[4][4] = {};

  for (int k0 = 0; k0 < K; k0 += 32) {
#pragma unroll
    for (int it = 0; it < 2; ++it) {
      const int slot = it * 4 + wv;
      const int r = slot * 16 + sr;
      gload_lds16(Ahi + (size_t)(tile_m + r) * K + k0 + sk, lA + slot * 512);
      if (HAS_LO)
        gload_lds16(Alo + (size_t)(tile_m + r) * K + k0 + sk, lAlo + slot * 512);
      gload_lds16(Bt + (size_t)(tile_n + r) * K + k0 + sk, lB + slot * 512);
    }
    __syncthreads();
    const int ro = lane & 15;
    const int qo = (lane >> 4) * 8;
    short8 af[4], bfr[4], al[4];
#pragma unroll
    for (int i = 0; i < 4; ++i) af[i] = *(const short8*)(lA + (wm + i * 16 + ro) * 32 + qo);
#pragma unroll
    for (int j = 0; j < 4; ++j) bfr[j] = *(const short8*)(lB + (wn + j * 16 + ro) * 32 + qo);
    if (HAS_LO) {
#pragma unroll
      for (int i = 0; i < 4; ++i) al[i] = *(const short8*)(lAlo + (wm + i * 16 + ro) * 32 + qo);
    }
#pragma unroll
    for (int i = 0; i < 4; ++i)
#pragma unroll
      for (int j = 0; j < 4; ++j) {
        acc[i][j] = __builtin_amdgcn_mfma_f32_16x16x32_bf16(af[i], bfr[j], acc[i][j], 0, 0, 0);
        if (HAS_LO)
          acc[i][j] = __builtin_amdgcn_mfma_f32_16x16x32_bf16(al[i], bfr[j], acc[i][j], 0, 0, 0);
      }
    __syncthreads();
  }

  const int colb = tile_n + wn + (lane & 15);
  const int rowb = tile_m + wm + (lane >> 4) * 4;
#pragma unroll
  for (int j = 0; j < 4; ++j) {
    const int col = colb + j * 16;
    const float bv = (col < N) ? bias[col] : 0.f;
#pragma unroll
    for (int i = 0; i < 4; ++i) {
#pragma unroll
      for (int v = 0; v < 4; ++v) {
        const int row = rowb + i * 16 + v;
        float val = acc[i][j][v] + bv;
        if (EPI == 0) {
          val = fmaxf(val, 0.f);
          const u16 hi = f2b(val);
          const float lo = val - b2f(hi);
          Chi[(size_t)row * N + col] = hi;
          Clo[(size_t)row * N + col] = f2b(lo);
        } else {
          if (col < N) Cf[(size_t)row * N + col] = val;
        }
      }
    }
  }
}

// ---------------------------------------------------------------------------
// Per-batch QP solver. 1 block / batch element, 256 threads.
// ---------------------------------------------------------------------------
__global__ __launch_bounds__(256) void qp_solve(const float* __restrict__ outbuf,
                                                void* __restrict__ xs,
                                                const int* __restrict__ flag) {
  __shared__ float p_s[NP];            // packed tril params (diag transformed)
  __shared__ float H_s[MQP * 65];      // H padded stride 65
  __shared__ float M_s[NQP * 66];      // P -> I+tau*P -> Minv (in-place GJ)
  __shared__ float q_s[NQP], b_s[MQP], v_s[NQP], w_s[MQP];
  __shared__ float rhs_s[NQP], xbar_s[NQP], lam_s[MQP], fvec[NQP];
  __shared__ float red[8];
  __shared__ float tau_s;

  const int t = threadIdx.x;
  const int isf = flag[0];
  const float* ob = outbuf + (size_t)blockIdx.x * NOUT;

  // ---- load ----
  for (int i = t; i < NP; i += 256) p_s[i] = ob[i];
  if (t < NQP) q_s[t] = ob[NP + t];
  for (int i = t; i < NHH; i += 256) {
    const int m = i >> 6, n = i & 63;
    H_s[m * 65 + n] = ob[NP + NQP + i];
  }
  if (t < MQP) b_s[t] = ob[NP + NQP + NHH + t];
  __syncthreads();

  // ---- diag: sqrt(MIN_EIG) + softplus ----
  if (t < NQP) {
    const int i = t + 1;
    const int d = i * (i + 1) / 2 - 1;
    const float x = p_s[d];
    p_s[d] = 0.1f + (fmaxf(x, 0.f) + log1pf(expf(-fabsf(x))));
  }
  __syncthreads();

  // ---- P = L L^T into M_s ----
  for (int e = t; e < NQP * NQP; e += 256) {
    const int i = e >> 6, j = e & 63;
    const int lim = (i < j ? i : j);
    const float* Li = p_s + i * (i + 1) / 2;
    const float* Lj = p_s + j * (j + 1) / 2;
    float s = 0.f;
    for (int kk = 0; kk <= lim; ++kk) s = fmaf(Li[kk], Lj[kk], s);
    M_s[i * 66 + j] = s;
  }

  // ---- power iteration (10) ----
  if (t < NQP) v_s[t] = 0.125f;
  __syncthreads();
  for (int pi = 0; pi < 10; ++pi) {
    if (t < MQP) {
      float s = 0.f;
      const float* Hr = H_s + t * 65;
      for (int n = 0; n < NQP; ++n) s = fmaf(Hr[n], v_s[n], s);
      w_s[t] = s;
    }
    __syncthreads();
    if (t < NQP) {
      float s = 0.f;
      for (int m = 0; m < MQP; ++m) s = fmaf(H_s[m * 65 + t], w_s[m], s);
      float ss = s * s;
      for (int o = 32; o > 0; o >>= 1) ss += __shfl_xor(ss, o, 64);
      v_s[t] = s / (sqrtf(ss) + 1e-12f);
    }
    __syncthreads();
  }
  // ---- sn = ||H v|| + 1e-6, tau = 0.9/sn ----
  if (t < MQP) {
    float s = 0.f;
    const float* Hr = H_s + t * 65;
    for (int n = 0; n < NQP; ++n) s = fmaf(Hr[n], v_s[n], s);
    float ss = s * s;
    for (int o = 32; o > 0; o >>= 1) ss += __shfl_xor(ss, o, 64);
    if ((t & 63) == 0) red[t >> 6] = ss;
  }
  __syncthreads();
  if (t == 0) tau_s = 0.9f / (sqrtf(red[0] + red[1]) + 1e-6f);
  __syncthreads();
  const float tau = tau_s;

  // ---- M = I + tau*P ----
  for (int e = t; e < NQP * NQP; e += 256) {
    const int i = e >> 6, j = e & 63;
    M_s[i * 66 + j] = (i == j ? 1.0f : 0.0f) + tau * M_s[i * 66 + j];
  }
  __syncthreads();

  // ---- in-place Gauss-Jordan inversion (SPD, pivots >= 1, no pivoting) ----
  for (int k = 0; k < NQP; ++k) {
    const float d = 1.0f / M_s[k * 66 + k];
    if (t < NQP) {
      if (t != k) M_s[k * 66 + t] *= d;
    } else if (t < 2 * NQP) {
      fvec[t - NQP] = M_s[(t - NQP) * 66 + k];
    }
    __syncthreads();
    for (int e = t; e < NQP * NQP; e += 256) {
      const int i = e >> 6, j = e & 63;
      if (i == k) {
        if (j == k) M_s[k * 66 + k] = d;
      } else if (j == k) {
        M_s[i * 66 + k] = -fvec[i] * d;
      } else {
        M_s[i * 66 + j] = fmaf(-fvec[i], M_s[k * 66 + j], M_s[i * 66 + j]);
      }
    }
    __syncthreads();
  }

  // ---- QP loop (50 PDHG iterations) ----
  float lam_r = 0.f, xp_r = 0.f;
  const float q_r = (t < NQP) ? q_s[t] : 0.f;
  const float b_r = (t < MQP) ? b_s[t] : 0.f;
  if (t < NQP) xbar_s[t] = 0.f;
  if (t < MQP) lam_s[t] = 0.f;
  __syncthreads();

  for (int it = 0; it < 50; ++it) {
    if (t < MQP) {
      float hx = 0.f;
      const float* Hr = H_s + t * 65;
      for (int n = 0; n < NQP; ++n) hx = fmaf(Hr[n], xbar_s[n], hx);
      lam_r = fmaxf(lam_r - tau * (hx + b_r), 0.f);
      lam_s[t] = lam_r;
    }
    __syncthreads();
    if (t < NQP) {
      float hl = 0.f;
      for (int m = 0; m < MQP; ++m) hl = fmaf(H_s[m * 65 + t], lam_s[m], hl);
      rhs_s[t] = xp_r + tau * (hl - q_r);
    }
    __syncthreads();
    if (t < NQP) {
      float xn = 0.f;
      const float* Mr = M_s + t * 66;
      for (int kk = 0; kk < NQP; ++kk) xn = fmaf(Mr[kk], rhs_s[kk], xn);
      xbar_s[t] = 2.f * xn - xp_r;
      xp_r = xn;
    }
    __syncthreads();
  }

  if (t < NQP) {
    const size_t oi = (size_t)blockIdx.x * NQP + t;
    if (isf) ((float*)xs)[oi] = xp_r;
    else     ((u16*)xs)[oi]   = f2b(xp_r);
  }
}

// ---------------------------------------------------------------------------
extern "C" void kernel_launch(void* const* d_in, const int* in_sizes, int n_in,
                              void* d_out, int out_size, void* d_ws, size_t ws_size,
                              hipStream_t stream) {
  const void* x  = d_in[0];
  const void* W1 = d_in[1];
  const void* b1 = d_in[2];
  const void* W2 = d_in[3];
  const void* b2 = d_in[4];
  const void* W3 = d_in[5];
  const void* b3 = d_in[6];

  char* ws = (char*)d_ws;
  size_t off = 0;
  auto take = [&](size_t bytes) -> char* {
    char* r = ws + off;
    off += (bytes + 255) & ~(size_t)255;
    return r;
  };
  int*   flag = (int*)take(256);
  float* bf1  = (float*)take(1024 * 4);
  float* bf2  = (float*)take(1024 * 4);
  float* bf3  = (float*)take((size_t)NOUT * 4);
  u16*   W3t  = (u16*)take((size_t)NOUTP * 1024 * 2);
  u16*   h2hi = (u16*)take(1024ull * 1024 * 2);
  u16*   h2lo = (u16*)take(1024ull * 1024 * 2);
  char*  region = take(1024ull * NOUT * 4);   // 42.86 MB: outf, overlaid below
  float* outf = (float*)region;
  // overlay (all dead before GEMM3 writes outf):
  u16* xb   = (u16*)(region + 0);                 // 1 MB
  u16* W1t  = (u16*)(region + (1u << 20));        // 1 MB
  u16* W2t  = (u16*)(region + (2u << 20));        // 2 MB
  u16* h1hi = (u16*)(region + (4u << 20));        // 2 MB
  u16* h1lo = (u16*)(region + (6u << 20));        // 2 MB
  (void)ws_size; (void)in_sizes; (void)n_in; (void)out_size;

  // dtype flag from W1
  detect_dtype<<<dim3(1), 256, 0, stream>>>((const u16*)W1, flag);

  // normalize inputs
  convert_bf16<<<dim3(512), 256, 0, stream>>>(x, xb, 1024 * 512, flag);
  convert_f32<<<dim3(4), 256, 0, stream>>>(b1, bf1, 1024, flag);
  convert_f32<<<dim3(4), 256, 0, stream>>>(b2, bf2, 1024, flag);
  convert_f32<<<dim3(41), 256, 0, stream>>>(b3, bf3, NOUT, flag);

  // weight transposes (K x N -> Npad x K), dtype-normalizing
  transpose_pad<<<dim3(32, 16), 256, 0, stream>>>(W1, W1t, 512, 1024, 1024, flag);
  transpose_pad<<<dim3(32, 32), 256, 0, stream>>>(W2, W2t, 1024, 1024, 1024, flag);
  transpose_pad<<<dim3(NOUTP / 32, 32), 256, 0, stream>>>(W3, W3t, 1024, NOUT, NOUTP, flag);

  // MLP
  gemm_bt<0, false><<<dim3(8, 8), 256, 0, stream>>>(xb, nullptr, W1t, bf1,
                                                    h1hi, h1lo, nullptr, 1024, 1024, 512);
  gemm_bt<0, true><<<dim3(8, 8), 256, 0, stream>>>(h1hi, h1lo, W2t, bf2,
                                                   h2hi, h2lo, nullptr, 1024, 1024, 1024);
  gemm_bt<1, true><<<dim3(NOUTP / 128, 8), 256, 0, stream>>>(h2hi, h2lo, W3t, bf3,
                                                             nullptr, nullptr, outf, 1024, NOUT, 1024);
  // QP solve
  qp_solve<<<dim3(1024), 256, 0, stream>>>(outf, d_out, flag);
}

// Round 3
// 618.129 us; speedup vs baseline: 1.3587x; 1.3587x over previous
//
#include <hip/hip_runtime.h>
#include <cstdint>

typedef unsigned short u16;
typedef __attribute__((ext_vector_type(8))) short short8;
typedef __attribute__((ext_vector_type(4))) float floatx4;
typedef __attribute__((ext_vector_type(4))) float f4;

#define NQP   64
#define MQP   128
#define NP    2080
#define NHH   8192
#define NOUT  10464   /* 2080 + 64 + 8192 + 128 */
#define NOUTP 10496   /* padded to 82*128 */

__device__ __forceinline__ float b2f(u16 u) {
  union { unsigned int i; float f; } v; v.i = ((unsigned int)u) << 16; return v.f;
}
__device__ __forceinline__ u16 f2b(float f) {
  union { float f; unsigned int i; } v; v.f = f;
  unsigned int r = v.i + 0x7fffu + ((v.i >> 16) & 1u);
  return (u16)(r >> 16);
}

// ---------------------------------------------------------------------------
// dtype detector: true-bf16 u16 words have exponent field ~[110,126];
// f32-mantissa words are ~uniform. flag=1 -> inputs are f32.
// ---------------------------------------------------------------------------
__global__ __launch_bounds__(256) void detect_dtype(const u16* __restrict__ w,
                                                    int* __restrict__ flag) {
  __shared__ int cnt;
  if (threadIdx.x == 0) cnt = 0;
  __syncthreads();
  int c = 0;
  for (int i = threadIdx.x; i < 16384; i += 256) {
    const int e = (w[i] >> 7) & 0xFF;
    if (e >= 130 || e <= 90) ++c;
  }
  atomicAdd(&cnt, c);
  __syncthreads();
  if (threadIdx.x == 0) flag[0] = (cnt > 3000) ? 1 : 0;
}

__device__ __forceinline__ u16 load_elem_bf16(const void* p, size_t idx, int isf32) {
  return isf32 ? f2b(((const float*)p)[idx]) : ((const u16*)p)[idx];
}

__global__ __launch_bounds__(256) void convert_bf16(const void* __restrict__ in,
                                                    u16* __restrict__ out, int n,
                                                    const int* __restrict__ flag) {
  const int isf = flag[0];
  for (int i = blockIdx.x * 256 + threadIdx.x; i < n; i += gridDim.x * 256)
    out[i] = load_elem_bf16(in, i, isf);
}

__global__ __launch_bounds__(256) void convert_f32(const void* __restrict__ in,
                                                   float* __restrict__ out, int n,
                                                   const int* __restrict__ flag) {
  const int isf = flag[0];
  for (int i = blockIdx.x * 256 + threadIdx.x; i < n; i += gridDim.x * 256)
    out[i] = isf ? ((const float*)in)[i] : b2f(((const u16*)in)[i]);
}

// ---------------------------------------------------------------------------
// Transpose (+ zero-pad rows)
// ---------------------------------------------------------------------------
__global__ __launch_bounds__(256) void transpose_pad(const void* __restrict__ in,
                                                     u16* __restrict__ out,
                                                     int K, int N, int Npad,
                                                     const int* __restrict__ flag) {
  __shared__ u16 tile[32][33];
  const int isf = flag[0];
  const int n0 = blockIdx.x * 32, k0 = blockIdx.y * 32;
  const int tx = threadIdx.x & 31, ty = threadIdx.x >> 5;
#pragma unroll
  for (int i = 0; i < 4; ++i) {
    const int k = k0 + ty + 8 * i, n = n0 + tx;
    tile[ty + 8 * i][tx] = (n < N) ? load_elem_bf16(in, (size_t)k * N + n, isf) : (u16)0;
  }
  __syncthreads();
#pragma unroll
  for (int i = 0; i < 4; ++i) {
    const int n = n0 + ty + 8 * i, k = k0 + tx;
    if (n < Npad) out[(size_t)n * K + k] = tile[tx][ty + 8 * i];
  }
}

// ---------------------------------------------------------------------------
// GEMM (m97-style 128x128 tile), unchanged from round 2.
// ---------------------------------------------------------------------------
__device__ __forceinline__ void gload_lds16(const u16* g, u16* l) {
  __builtin_amdgcn_global_load_lds((const __attribute__((address_space(1))) void*)g,
                                   (__attribute__((address_space(3))) void*)l, 16, 0, 0);
}

template <int EPI, bool HAS_LO>
__global__ __launch_bounds__(256) void gemm_bt(const u16* __restrict__ Ahi, const u16* __restrict__ Alo,
                                               const u16* __restrict__ Bt,  const float* __restrict__ bias,
                                               u16* __restrict__ Chi, u16* __restrict__ Clo,
                                               float* __restrict__ Cf,
                                               int M, int N, int K) {
  __shared__ __align__(16) u16 lA[128 * 32];
  __shared__ __align__(16) u16 lAlo[128 * 32];
  __shared__ __align__(16) u16 lB[128 * 32];
  const int tile_n = blockIdx.x * 128;
  const int tile_m = blockIdx.y * 128;
  const int lane = threadIdx.x & 63;
  const int wv   = threadIdx.x >> 6;
  const int wm = (wv & 1) * 64;
  const int wn = (wv >> 1) * 64;
  const int sr = lane >> 2;
  const int sk = (lane & 3) * 8;
  floatx4 acc[4][4] = {};

  for (int k0 = 0; k0 < K; k0 += 32) {
#pragma unroll
    for (int it = 0; it < 2; ++it) {
      const int slot = it * 4 + wv;
      const int r = slot * 16 + sr;
      gload_lds16(Ahi + (size_t)(tile_m + r) * K + k0 + sk, lA + slot * 512);
      if (HAS_LO)
        gload_lds16(Alo + (size_t)(tile_m + r) * K + k0 + sk, lAlo + slot * 512);
      gload_lds16(Bt + (size_t)(tile_n + r) * K + k0 + sk, lB + slot * 512);
    }
    __syncthreads();
    const int ro = lane & 15;
    const int qo = (lane >> 4) * 8;
    short8 af[4], bfr[4], al[4];
#pragma unroll
    for (int i = 0; i < 4; ++i) af[i] = *(const short8*)(lA + (wm + i * 16 + ro) * 32 + qo);
#pragma unroll
    for (int j = 0; j < 4; ++j) bfr[j] = *(const short8*)(lB + (wn + j * 16 + ro) * 32 + qo);
    if (HAS_LO) {
#pragma unroll
      for (int i = 0; i < 4; ++i) al[i] = *(const short8*)(lAlo + (wm + i * 16 + ro) * 32 + qo);
    }
#pragma unroll
    for (int i = 0; i < 4; ++i)
#pragma unroll
      for (int j = 0; j < 4; ++j) {
        acc[i][j] = __builtin_amdgcn_mfma_f32_16x16x32_bf16(af[i], bfr[j], acc[i][j], 0, 0, 0);
        if (HAS_LO)
          acc[i][j] = __builtin_amdgcn_mfma_f32_16x16x32_bf16(al[i], bfr[j], acc[i][j], 0, 0, 0);
      }
    __syncthreads();
  }

  const int colb = tile_n + wn + (lane & 15);
  const int rowb = tile_m + wm + (lane >> 4) * 4;
#pragma unroll
  for (int j = 0; j < 4; ++j) {
    const int col = colb + j * 16;
    const float bv = (col < N) ? bias[col] : 0.f;
#pragma unroll
    for (int i = 0; i < 4; ++i) {
#pragma unroll
      for (int v = 0; v < 4; ++v) {
        const int row = rowb + i * 16 + v;
        float val = acc[i][j][v] + bv;
        if (EPI == 0) {
          val = fmaxf(val, 0.f);
          const u16 hi = f2b(val);
          const float lo = val - b2f(hi);
          Chi[(size_t)row * N + col] = hi;
          Clo[(size_t)row * N + col] = f2b(lo);
        } else {
          if (col < N) Cf[(size_t)row * N + col] = val;
        }
      }
    }
  }
}

// ---------------------------------------------------------------------------
// QP solver helpers
// ---------------------------------------------------------------------------
__device__ __forceinline__ f4 ld4s(const float* p) { return *(const f4*)p; }
__device__ __forceinline__ void st4s(float* p, f4 v) { *(f4*)p = v; }
__device__ __forceinline__ float dot4(f4 a, f4 b) {
  return fmaf(a.x, b.x, fmaf(a.y, b.y, fmaf(a.z, b.z, a.w * b.w)));
}
__device__ __forceinline__ f4 shx4(f4 v, int m) {
  f4 r;
  r.x = __shfl_xor(v.x, m, 64); r.y = __shfl_xor(v.y, m, 64);
  r.z = __shfl_xor(v.z, m, 64); r.w = __shfl_xor(v.w, m, 64);
  return r;
}
__device__ __forceinline__ f4 max04(f4 a) {
  f4 r; r.x = fmaxf(a.x, 0.f); r.y = fmaxf(a.y, 0.f);
  r.z = fmaxf(a.z, 0.f); r.w = fmaxf(a.w, 0.f); return r;
}
// XOR-swizzled base of float4 group cg in row m (stride 64 floats).
// phys_group = cg ^ (m & 15): row reads (cg varies) and column reads (m varies)
// both land at the LDS structural minimum.
__device__ __forceinline__ int hQ(int m, int cg) {
  return (m << 6) + ((cg ^ (m & 15)) << 2);
}

// ---------------------------------------------------------------------------
// Per-batch QP solver. 1 block / batch element, 256 threads, f4-everything.
// ---------------------------------------------------------------------------
__global__ __launch_bounds__(256) void qp_solve(const float* __restrict__ outbuf,
                                                void* __restrict__ xs,
                                                const int* __restrict__ flag) {
  __shared__ float H_s[128 * 64];     // 32 KB, swizzled
  __shared__ float M_s[64 * 64];      // 16 KB, swizzled (P -> I+tau*P -> Minv)
  __shared__ float lam_s[128], w_s[128], b_s[128];
  __shared__ float xbar_s[64], xp_s[64], rhs_s[64], q_s[64], v_s[64], fvec[64];
  __shared__ float red[4];
  __shared__ float d_s, tau_s;

  const int t = threadIdx.x;
  const int l = t & 63, w = t >> 6;
  const int r = l & 15;          // reduction-lane id
  const int g = l >> 4;          // 0..3
  const int mgA = 8 * w + g;     // phase-A output f4-groups (m = 4*mg..+3)
  const int mgB = mgA + 4;
  const int ng  = 4 * w + g;     // phase-B/C output f4-group (n = 4*ng..+3)
  const int isf = flag[0];
  const float* ob = outbuf + (size_t)blockIdx.x * NOUT;

  float* p_s = H_s;  // alias: packed tril params live here until H is loaded

  // ---- load p, q, b ----
  for (int i = t; i < NP; i += 256) p_s[i] = ob[i];
  if (t < 64) q_s[t] = ob[NP + t];
  if (t >= 64 && t < 192) b_s[t - 64] = ob[NP + NQP + NHH + (t - 64)];
  __syncthreads();

  // ---- diag: sqrt(MIN_EIG) + softplus ----
  if (t < 64) {
    const int i = t + 1;
    const int d = i * (i + 1) / 2 - 1;
    const float xv = p_s[d];
    p_s[d] = 0.1f + (fmaxf(xv, 0.f) + log1pf(expf(-fabsf(xv))));
  }
  __syncthreads();

  // ---- P = L L^T (triangle + mirror) into M_s (swizzled) ----
  for (int e = t; e < NP; e += 256) {
    int i = (int)((sqrtf(8.f * (float)e + 1.f) - 1.f) * 0.5f);
    while ((i + 1) * (i + 2) / 2 <= e) ++i;
    while (i * (i + 1) / 2 > e) --i;
    const int j = e - i * (i + 1) / 2;   // j <= i
    const float* Li = p_s + i * (i + 1) / 2;
    const float* Lj = p_s + j * (j + 1) / 2;
    float s = 0.f;
    for (int kk = 0; kk <= j; ++kk) s = fmaf(Li[kk], Lj[kk], s);
    M_s[hQ(i, j >> 2) + (j & 3)] = s;
    M_s[hQ(j, i >> 2) + (i & 3)] = s;
  }
  __syncthreads();

  // ---- load H (overwrites p region), swizzled ----
  for (int i = t; i < NHH; i += 256) {
    const int m = i >> 6, n = i & 63;
    H_s[hQ(m, n >> 2) + (n & 3)] = ob[NP + NQP + i];
  }
  if (t < 64) { v_s[t] = 0.125f; xbar_s[t] = 0.f; xp_s[t] = 0.f; }
  if (t >= 64 && t < 192) lam_s[t - 64] = 0.f;
  __syncthreads();

  // ---- power iteration (10) ----
  for (int pi = 0; pi < 10; ++pi) {
    // t1 = H v  (A-structure) -> w_s
    {
      const f4 xb = ld4s(&v_s[4 * r]);
      f4 sA, sB;
      sA.x = dot4(ld4s(&H_s[hQ(4 * mgA + 0, r)]), xb);
      sA.y = dot4(ld4s(&H_s[hQ(4 * mgA + 1, r)]), xb);
      sA.z = dot4(ld4s(&H_s[hQ(4 * mgA + 2, r)]), xb);
      sA.w = dot4(ld4s(&H_s[hQ(4 * mgA + 3, r)]), xb);
      sB.x = dot4(ld4s(&H_s[hQ(4 * mgB + 0, r)]), xb);
      sB.y = dot4(ld4s(&H_s[hQ(4 * mgB + 1, r)]), xb);
      sB.z = dot4(ld4s(&H_s[hQ(4 * mgB + 2, r)]), xb);
      sB.w = dot4(ld4s(&H_s[hQ(4 * mgB + 3, r)]), xb);
#pragma unroll
      for (int mm = 1; mm <= 8; mm <<= 1) { sA += shx4(sA, mm); sB += shx4(sB, mm); }
      if (r == 0) st4s(&w_s[4 * mgA], sA);
      else if (r == 1) st4s(&w_s[4 * mgB], sB);
    }
    __syncthreads();
    // u = H^T t1 (B-structure), normalize -> v_s
    {
      f4 u = {0.f, 0.f, 0.f, 0.f};
#pragma unroll
      for (int k = 0; k < 8; ++k) {
        const int m = r + 16 * k;
        u += ld4s(&H_s[hQ(m, ng)]) * w_s[m];
      }
#pragma unroll
      for (int mm = 1; mm <= 8; mm <<= 1) u += shx4(u, mm);
      float ss = dot4(u, u);
      ss += __shfl_xor(ss, 16, 64);
      ss += __shfl_xor(ss, 32, 64);
      if (l == 0) red[w] = ss;
      __syncthreads();
      const float tot = red[0] + red[1] + red[2] + red[3];
      if (r == 0) st4s(&v_s[4 * ng], u * (1.0f / (sqrtf(tot) + 1e-12f)));
    }
    __syncthreads();
  }

  // ---- sn = ||H v|| + 1e-6, tau = 0.9/sn ----
  {
    const f4 xb = ld4s(&v_s[4 * r]);
    f4 sA, sB;
    sA.x = dot4(ld4s(&H_s[hQ(4 * mgA + 0, r)]), xb);
    sA.y = dot4(ld4s(&H_s[hQ(4 * mgA + 1, r)]), xb);
    sA.z = dot4(ld4s(&H_s[hQ(4 * mgA + 2, r)]), xb);
    sA.w = dot4(ld4s(&H_s[hQ(4 * mgA + 3, r)]), xb);
    sB.x = dot4(ld4s(&H_s[hQ(4 * mgB + 0, r)]), xb);
    sB.y = dot4(ld4s(&H_s[hQ(4 * mgB + 1, r)]), xb);
    sB.z = dot4(ld4s(&H_s[hQ(4 * mgB + 2, r)]), xb);
    sB.w = dot4(ld4s(&H_s[hQ(4 * mgB + 3, r)]), xb);
#pragma unroll
    for (int mm = 1; mm <= 8; mm <<= 1) { sA += shx4(sA, mm); sB += shx4(sB, mm); }
    float ss = dot4(sA, sA) + dot4(sB, sB);
    ss += __shfl_xor(ss, 16, 64);
    ss += __shfl_xor(ss, 32, 64);
    if (l == 0) red[w] = ss;
    __syncthreads();
    if (t == 0) tau_s = 0.9f / (sqrtf(red[0] + red[1] + red[2] + red[3]) + 1e-6f);
    __syncthreads();
  }
  const float tau = tau_s;

  // ---- M = I + tau*P (iterate physical slots) ----
  for (int e = t; e < 4096; e += 256) {
    const int i = e >> 6, pc = e & 63;
    const int j = ((((pc >> 2) ^ (i & 15)) << 2) | (pc & 3));  // logical col
    M_s[e] = (i == j ? 1.0f : 0.0f) + tau * M_s[e];
  }
  __syncthreads();

  // ---- in-place Gauss-Jordan inversion (SPD, pivots >= 1) ----
  for (int k = 0; k < 64; ++k) {
    if (t == 0) d_s = 1.0f / M_s[hQ(k, k >> 2) + (k & 3)];
    __syncthreads();
    const float d = d_s;
    if (t < 64) {
      const int idx = hQ(k, t >> 2) + (t & 3);
      float val = M_s[idx] * d;
      if (t == k) val = d;
      M_s[idx] = val;
    } else if (t < 128) {
      const int i = t - 64;
      float fv = 0.f;
      if (i != k) {
        const int idx = hQ(i, k >> 2) + (k & 3);
        fv = M_s[idx];
        M_s[idx] = 0.f;
      }
      fvec[i] = fv;
    }
    __syncthreads();
#pragma unroll
    for (int p4 = 0; p4 < 4; ++p4) {
      const int e = t + 256 * p4;
      const int i = e >> 4, pg = e & 15;
      if (i != k) {
        const int jg = pg ^ (i & 15);      // logical group of this slot
        f4 mi = ld4s(&M_s[(i << 6) + (pg << 2)]);
        const f4 mk = ld4s(&M_s[hQ(k, jg)]);
        const float f = fvec[i];
        mi.x = fmaf(-f, mk.x, mi.x); mi.y = fmaf(-f, mk.y, mi.y);
        mi.z = fmaf(-f, mk.z, mi.z); mi.w = fmaf(-f, mk.w, mi.w);
        st4s(&M_s[(i << 6) + (pg << 2)], mi);
      }
    }
    __syncthreads();
  }

  // ---- PDHG loop (50 iterations), 3 syncs/iter ----
  for (int it = 0; it < 50; ++it) {
    // A: lam = relu(lam - tau*(H xbar + b))
    {
      const f4 xb = ld4s(&xbar_s[4 * r]);
      f4 sA, sB;
      sA.x = dot4(ld4s(&H_s[hQ(4 * mgA + 0, r)]), xb);
      sA.y = dot4(ld4s(&H_s[hQ(4 * mgA + 1, r)]), xb);
      sA.z = dot4(ld4s(&H_s[hQ(4 * mgA + 2, r)]), xb);
      sA.w = dot4(ld4s(&H_s[hQ(4 * mgA + 3, r)]), xb);
      sB.x = dot4(ld4s(&H_s[hQ(4 * mgB + 0, r)]), xb);
      sB.y = dot4(ld4s(&H_s[hQ(4 * mgB + 1, r)]), xb);
      sB.z = dot4(ld4s(&H_s[hQ(4 * mgB + 2, r)]), xb);
      sB.w = dot4(ld4s(&H_s[hQ(4 * mgB + 3, r)]), xb);
#pragma unroll
      for (int mm = 1; mm <= 8; mm <<= 1) { sA += shx4(sA, mm); sB += shx4(sB, mm); }
      if (r == 0) {
        const f4 lam = ld4s(&lam_s[4 * mgA]);
        const f4 bb  = ld4s(&b_s[4 * mgA]);
        st4s(&lam_s[4 * mgA], max04(lam - (sA + bb) * tau));
      } else if (r == 1) {
        const f4 lam = ld4s(&lam_s[4 * mgB]);
        const f4 bb  = ld4s(&b_s[4 * mgB]);
        st4s(&lam_s[4 * mgB], max04(lam - (sB + bb) * tau));
      }
    }
    __syncthreads();
    // B: rhs = xp + tau*(H^T lam - q)
    {
      f4 u = {0.f, 0.f, 0.f, 0.f};
#pragma unroll
      for (int k = 0; k < 8; ++k) {
        const int m = r + 16 * k;
        u += ld4s(&H_s[hQ(m, ng)]) * lam_s[m];
      }
#pragma unroll
      for (int mm = 1; mm <= 8; mm <<= 1) u += shx4(u, mm);
      if (r == 0) {
        const f4 xp = ld4s(&xp_s[4 * ng]);
        const f4 qq = ld4s(&q_s[4 * ng]);
        st4s(&rhs_s[4 * ng], xp + (u - qq) * tau);
      }
    }
    __syncthreads();
    // C: xn = Minv rhs (Minv symmetric -> row reads)
    {
      f4 xn = {0.f, 0.f, 0.f, 0.f};
#pragma unroll
      for (int k = 0; k < 4; ++k) {
        const int kk = r + 16 * k;
        xn += ld4s(&M_s[hQ(kk, ng)]) * rhs_s[kk];
      }
#pragma unroll
      for (int mm = 1; mm <= 8; mm <<= 1) xn += shx4(xn, mm);
      if (r == 0) {
        const f4 xpo = ld4s(&xp_s[4 * ng]);
        st4s(&xp_s[4 * ng], xn);
        st4s(&xbar_s[4 * ng], xn + xn - xpo);
      }
    }
    __syncthreads();
  }

  if (t < 64) {
    const size_t oi = (size_t)blockIdx.x * NQP + t;
    const float val = xp_s[t];
    if (isf) ((float*)xs)[oi] = val;
    else     ((u16*)xs)[oi]   = f2b(val);
  }
}

// ---------------------------------------------------------------------------
extern "C" void kernel_launch(void* const* d_in, const int* in_sizes, int n_in,
                              void* d_out, int out_size, void* d_ws, size_t ws_size,
                              hipStream_t stream) {
  const void* x  = d_in[0];
  const void* W1 = d_in[1];
  const void* b1 = d_in[2];
  const void* W2 = d_in[3];
  const void* b2 = d_in[4];
  const void* W3 = d_in[5];
  const void* b3 = d_in[6];

  char* ws = (char*)d_ws;
  size_t off = 0;
  auto take = [&](size_t bytes) -> char* {
    char* r = ws + off;
    off += (bytes + 255) & ~(size_t)255;
    return r;
  };
  int*   flag = (int*)take(256);
  float* bf1  = (float*)take(1024 * 4);
  float* bf2  = (float*)take(1024 * 4);
  float* bf3  = (float*)take((size_t)NOUT * 4);
  u16*   W3t  = (u16*)take((size_t)NOUTP * 1024 * 2);
  u16*   h2hi = (u16*)take(1024ull * 1024 * 2);
  u16*   h2lo = (u16*)take(1024ull * 1024 * 2);
  char*  region = take(1024ull * NOUT * 4);   // outf, overlaid below
  float* outf = (float*)region;
  u16* xb   = (u16*)(region + 0);                 // 1 MB
  u16* W1t  = (u16*)(region + (1u << 20));        // 1 MB
  u16* W2t  = (u16*)(region + (2u << 20));        // 2 MB
  u16* h1hi = (u16*)(region + (4u << 20));        // 2 MB
  u16* h1lo = (u16*)(region + (6u << 20));        // 2 MB
  (void)ws_size; (void)in_sizes; (void)n_in; (void)out_size;

  detect_dtype<<<dim3(1), 256, 0, stream>>>((const u16*)W1, flag);

  convert_bf16<<<dim3(512), 256, 0, stream>>>(x, xb, 1024 * 512, flag);
  convert_f32<<<dim3(4), 256, 0, stream>>>(b1, bf1, 1024, flag);
  convert_f32<<<dim3(4), 256, 0, stream>>>(b2, bf2, 1024, flag);
  convert_f32<<<dim3(41), 256, 0, stream>>>(b3, bf3, NOUT, flag);

  transpose_pad<<<dim3(32, 16), 256, 0, stream>>>(W1, W1t, 512, 1024, 1024, flag);
  transpose_pad<<<dim3(32, 32), 256, 0, stream>>>(W2, W2t, 1024, 1024, 1024, flag);
  transpose_pad<<<dim3(NOUTP / 32, 32), 256, 0, stream>>>(W3, W3t, 1024, NOUT, NOUTP, flag);

  gemm_bt<0, false><<<dim3(8, 8), 256, 0, stream>>>(xb, nullptr, W1t, bf1,
                                                    h1hi, h1lo, nullptr, 1024, 1024, 512);
  gemm_bt<0, true><<<dim3(8, 8), 256, 0, stream>>>(h1hi, h1lo, W2t, bf2,
                                                   h2hi, h2lo, nullptr, 1024, 1024, 1024);
  gemm_bt<1, true><<<dim3(NOUTP / 128, 8), 256, 0, stream>>>(h2hi, h2lo, W3t, bf3,
                                                             nullptr, nullptr, outf, 1024, NOUT, 1024);
  qp_solve<<<dim3(1024), 256, 0, stream>>>(outf, d_out, flag);
}

// Round 4
// 519.200 us; speedup vs baseline: 1.6176x; 1.1905x over previous
//
#include <hip/hip_runtime.h>
#include <cstdint>

typedef unsigned short u16;
typedef __attribute__((ext_vector_type(8))) short short8;
typedef __attribute__((ext_vector_type(4))) float floatx4;
typedef __attribute__((ext_vector_type(4))) float f4;

#define NQP   64
#define MQP   128
#define NP    2080
#define NHH   8192
#define NOUT  10464   /* 2080 + 64 + 8192 + 128 */
#define NOUTP 10496   /* padded to 82*128 */

__device__ __forceinline__ float b2f(u16 u) {
  union { unsigned int i; float f; } v; v.i = ((unsigned int)u) << 16; return v.f;
}
__device__ __forceinline__ u16 f2b(float f) {
  union { float f; unsigned int i; } v; v.f = f;
  unsigned int r = v.i + 0x7fffu + ((v.i >> 16) & 1u);
  return (u16)(r >> 16);
}

// ---------------------------------------------------------------------------
// dtype detector (flag=1 -> inputs are f32)
// ---------------------------------------------------------------------------
__global__ __launch_bounds__(256) void detect_dtype(const u16* __restrict__ w,
                                                    int* __restrict__ flag) {
  __shared__ int cnt;
  if (threadIdx.x == 0) cnt = 0;
  __syncthreads();
  int c = 0;
  for (int i = threadIdx.x; i < 16384; i += 256) {
    const int e = (w[i] >> 7) & 0xFF;
    if (e >= 130 || e <= 90) ++c;
  }
  atomicAdd(&cnt, c);
  __syncthreads();
  if (threadIdx.x == 0) flag[0] = (cnt > 3000) ? 1 : 0;
}

__device__ __forceinline__ u16 load_elem_bf16(const void* p, size_t idx, int isf32) {
  return isf32 ? f2b(((const float*)p)[idx]) : ((const u16*)p)[idx];
}

__global__ __launch_bounds__(256) void convert_bf16(const void* __restrict__ in,
                                                    u16* __restrict__ out, int n,
                                                    const int* __restrict__ flag) {
  const int isf = flag[0];
  for (int i = blockIdx.x * 256 + threadIdx.x; i < n; i += gridDim.x * 256)
    out[i] = load_elem_bf16(in, i, isf);
}

__global__ __launch_bounds__(256) void convert_f32(const void* __restrict__ in,
                                                   float* __restrict__ out, int n,
                                                   const int* __restrict__ flag) {
  const int isf = flag[0];
  for (int i = blockIdx.x * 256 + threadIdx.x; i < n; i += gridDim.x * 256)
    out[i] = isf ? ((const float*)in)[i] : b2f(((const u16*)in)[i]);
}

// ---------------------------------------------------------------------------
// Transpose (+ zero-pad rows)
// ---------------------------------------------------------------------------
__global__ __launch_bounds__(256) void transpose_pad(const void* __restrict__ in,
                                                     u16* __restrict__ out,
                                                     int K, int N, int Npad,
                                                     const int* __restrict__ flag) {
  __shared__ u16 tile[32][33];
  const int isf = flag[0];
  const int n0 = blockIdx.x * 32, k0 = blockIdx.y * 32;
  const int tx = threadIdx.x & 31, ty = threadIdx.x >> 5;
#pragma unroll
  for (int i = 0; i < 4; ++i) {
    const int k = k0 + ty + 8 * i, n = n0 + tx;
    tile[ty + 8 * i][tx] = (n < N) ? load_elem_bf16(in, (size_t)k * N + n, isf) : (u16)0;
  }
  __syncthreads();
#pragma unroll
  for (int i = 0; i < 4; ++i) {
    const int n = n0 + ty + 8 * i, k = k0 + tx;
    if (n < Npad) out[(size_t)n * K + k] = tile[tx][ty + 8 * i];
  }
}

// ---------------------------------------------------------------------------
// GEMM (m97-style 128x128 tile), unchanged.
// ---------------------------------------------------------------------------
__device__ __forceinline__ void gload_lds16(const u16* g, u16* l) {
  __builtin_amdgcn_global_load_lds((const __attribute__((address_space(1))) void*)g,
                                   (__attribute__((address_space(3))) void*)l, 16, 0, 0);
}

template <int EPI, bool HAS_LO>
__global__ __launch_bounds__(256) void gemm_bt(const u16* __restrict__ Ahi, const u16* __restrict__ Alo,
                                               const u16* __restrict__ Bt,  const float* __restrict__ bias,
                                               u16* __restrict__ Chi, u16* __restrict__ Clo,
                                               float* __restrict__ Cf,
                                               int M, int N, int K) {
  __shared__ __align__(16) u16 lA[128 * 32];
  __shared__ __align__(16) u16 lAlo[128 * 32];
  __shared__ __align__(16) u16 lB[128 * 32];
  const int tile_n = blockIdx.x * 128;
  const int tile_m = blockIdx.y * 128;
  const int lane = threadIdx.x & 63;
  const int wv   = threadIdx.x >> 6;
  const int wm = (wv & 1) * 64;
  const int wn = (wv >> 1) * 64;
  const int sr = lane >> 2;
  const int sk = (lane & 3) * 8;
  floatx4 acc[4][4] = {};

  for (int k0 = 0; k0 < K; k0 += 32) {
#pragma unroll
    for (int it = 0; it < 2; ++it) {
      const int slot = it * 4 + wv;
      const int r = slot * 16 + sr;
      gload_lds16(Ahi + (size_t)(tile_m + r) * K + k0 + sk, lA + slot * 512);
      if (HAS_LO)
        gload_lds16(Alo + (size_t)(tile_m + r) * K + k0 + sk, lAlo + slot * 512);
      gload_lds16(Bt + (size_t)(tile_n + r) * K + k0 + sk, lB + slot * 512);
    }
    __syncthreads();
    const int ro = lane & 15;
    const int qo = (lane >> 4) * 8;
    short8 af[4], bfr[4], al[4];
#pragma unroll
    for (int i = 0; i < 4; ++i) af[i] = *(const short8*)(lA + (wm + i * 16 + ro) * 32 + qo);
#pragma unroll
    for (int j = 0; j < 4; ++j) bfr[j] = *(const short8*)(lB + (wn + j * 16 + ro) * 32 + qo);
    if (HAS_LO) {
#pragma unroll
      for (int i = 0; i < 4; ++i) al[i] = *(const short8*)(lAlo + (wm + i * 16 + ro) * 32 + qo);
    }
#pragma unroll
    for (int i = 0; i < 4; ++i)
#pragma unroll
      for (int j = 0; j < 4; ++j) {
        acc[i][j] = __builtin_amdgcn_mfma_f32_16x16x32_bf16(af[i], bfr[j], acc[i][j], 0, 0, 0);
        if (HAS_LO)
          acc[i][j] = __builtin_amdgcn_mfma_f32_16x16x32_bf16(al[i], bfr[j], acc[i][j], 0, 0, 0);
      }
    __syncthreads();
  }

  const int colb = tile_n + wn + (lane & 15);
  const int rowb = tile_m + wm + (lane >> 4) * 4;
#pragma unroll
  for (int j = 0; j < 4; ++j) {
    const int col = colb + j * 16;
    const float bv = (col < N) ? bias[col] : 0.f;
#pragma unroll
    for (int i = 0; i < 4; ++i) {
#pragma unroll
      for (int v = 0; v < 4; ++v) {
        const int row = rowb + i * 16 + v;
        float val = acc[i][j][v] + bv;
        if (EPI == 0) {
          val = fmaxf(val, 0.f);
          const u16 hi = f2b(val);
          const float lo = val - b2f(hi);
          Chi[(size_t)row * N + col] = hi;
          Clo[(size_t)row * N + col] = f2b(lo);
        } else {
          if (col < N) Cf[(size_t)row * N + col] = val;
        }
      }
    }
  }
}

// ---------------------------------------------------------------------------
// QP helpers
// ---------------------------------------------------------------------------
__device__ __forceinline__ f4 ld4s(const float* p) { return *(const f4*)p; }
__device__ __forceinline__ void st4s(float* p, f4 v) { *(f4*)p = v; }
__device__ __forceinline__ float dot4(f4 a, f4 b) {
  return fmaf(a.x, b.x, fmaf(a.y, b.y, fmaf(a.z, b.z, a.w * b.w)));
}
__device__ __forceinline__ f4 shx4(f4 v, int m) {
  f4 r;
  r.x = __shfl_xor(v.x, m, 64); r.y = __shfl_xor(v.y, m, 64);
  r.z = __shfl_xor(v.z, m, 64); r.w = __shfl_xor(v.w, m, 64);
  return r;
}
// XOR-swizzled float-index of f4 group g in row m (row stride 64 floats).
__device__ __forceinline__ int hQ(int m, int g) {
  return (m << 6) + (((g ^ (m & 15))) << 2);
}

// ---------------------------------------------------------------------------
// Per-batch QP solver. 1 block/batch, 256 thr, Minv in registers, 4 blk/CU.
// ---------------------------------------------------------------------------
__global__ __launch_bounds__(256, 4) void qp_solve(const float* __restrict__ outbuf,
                                                   void* __restrict__ xs,
                                                   const int* __restrict__ flag) {
  __shared__ __align__(16) float H_s[8192];       // 32 KB (setup: Ld stride-68 + packed p)
  __shared__ __align__(16) float lam_s[128];      // also power-iter w staging
  __shared__ __align__(16) float b_s[128];
  __shared__ __align__(16) float part_s[4][64];
  __shared__ __align__(16) float xb2[2][64];
  __shared__ __align__(16) float xp2[2][64];
  __shared__ __align__(16) float q_s[64];
  __shared__ __align__(16) float buf2[2][64];
  __shared__ float tau_sh;

  const int t = threadIdx.x;
  const int w = t >> 6, l = t & 63;
  const int am = 32 * w + (l >> 1), as = l & 1;    // phase-A: row m, half s
  const int bg = l & 15, bc = l >> 4;              // phase-B: n-group, m-chunk
  const int ci = 16 * w + (l >> 2), cc = l & 3;    // M ownership: row i, col-slice c
  const int isf = flag[0];
  const float* ob = outbuf + (size_t)blockIdx.x * NOUT;

  // ---- setup: dense L (stride 68, zero-padded) + packed p ----
  float* Ld = H_s;                 // [0 .. 64*68) = 4352 floats
  float* ps = H_s + 4352;          // [4352 .. 6432)
  for (int e = t; e < 4352; e += 256) Ld[e] = 0.f;
  for (int e = t; e < NP; e += 256) ps[e] = ob[e];
  if (t < 64) q_s[t] = ob[NP + t];
  if (t >= 128 && t < 256) b_s[t - 128] = ob[NP + NQP + NHH + (t - 128)];
  __syncthreads();
  if (t < 64) {
    const int i = t + 1;
    const int d = i * (i + 1) / 2 - 1;
    const float xv = ps[d];
    ps[d] = 0.1f + (fmaxf(xv, 0.f) + log1pf(expf(-fabsf(xv))));
  }
  __syncthreads();
  for (int e = t; e < NP; e += 256) {
    int i = (int)((sqrtf(8.f * (float)e + 1.f) - 1.f) * 0.5f);
    while ((i + 1) * (i + 2) / 2 <= e) ++i;
    while (i * (i + 1) / 2 > e) --i;
    const int j = e - i * (i + 1) / 2;   // j <= i
    Ld[i * 68 + j] = ps[e];
  }
  __syncthreads();

  // ---- P = L L^T into registers M[16] (row ci, cols 16cc..16cc+15) ----
  float M[16];
#pragma unroll
  for (int jj = 0; jj < 16; ++jj) M[jj] = 0.f;
#pragma unroll
  for (int h = 0; h < 2; ++h) {
    f4 Lr[8];
#pragma unroll
    for (int g = 0; g < 8; ++g) Lr[g] = ld4s(&Ld[ci * 68 + (h * 8 + g) * 4]);
#pragma unroll
    for (int jj = 0; jj < 16; ++jj) {
      const int j = 16 * cc + jj;
      float s = 0.f;
#pragma unroll
      for (int g = 0; g < 8; ++g) s += dot4(Lr[g], ld4s(&Ld[j * 68 + (h * 8 + g) * 4]));
      M[jj] += s;
    }
  }
  __syncthreads();   // done with Ld/ps

  // ---- load H (swizzled f32), init power vector ----
  for (int e = t; e < NHH; e += 256) {
    const int m = e >> 6, n = e & 63;
    H_s[hQ(m, n >> 2) + (n & 3)] = ob[NP + NQP + e];
  }
  if (t < 64) { xb2[0][t] = 0.125f; }
  __syncthreads();

  // ---- power iteration (10): v in xb2[0], w staged in lam_s ----
  for (int pi = 0; pi < 10; ++pi) {
    {
      float s = 0.f;
#pragma unroll
      for (int k = 0; k < 8; ++k) {
        const int g = 8 * as + k;
        s += dot4(ld4s(&H_s[hQ(am, g)]), ld4s(&xb2[0][4 * g]));
      }
      s += __shfl_xor(s, 1, 64);
      if (as == 0) lam_s[am] = s;
    }
    __syncthreads();
    {
      f4 u = {0.f, 0.f, 0.f, 0.f};
#pragma unroll
      for (int k = 0; k < 8; ++k) {
        const int m = 32 * w + 8 * bc + k;
        u += ld4s(&H_s[hQ(m, bg)]) * lam_s[m];
      }
      u += shx4(u, 16); u += shx4(u, 32);
      if (l < 16) st4s(&part_s[w][4 * bg], u);
    }
    __syncthreads();
    if (t < 64) {
      const float u = part_s[0][t] + part_s[1][t] + part_s[2][t] + part_s[3][t];
      float ss = u * u;
#pragma unroll
      for (int o = 1; o <= 32; o <<= 1) ss += __shfl_xor(ss, o, 64);
      xb2[0][t] = u / (sqrtf(ss) + 1e-12f);
    }
    __syncthreads();
  }
  // ---- tau = 0.9 / (||H v|| + 1e-6) ----
  {
    float s = 0.f;
#pragma unroll
    for (int k = 0; k < 8; ++k) {
      const int g = 8 * as + k;
      s += dot4(ld4s(&H_s[hQ(am, g)]), ld4s(&xb2[0][4 * g]));
    }
    s += __shfl_xor(s, 1, 64);
    if (as == 0) lam_s[am] = s;
  }
  __syncthreads();
  if (t < 64) {
    const float a = lam_s[t], bb = lam_s[t + 64];
    float ss = a * a + bb * bb;
#pragma unroll
    for (int o = 1; o <= 32; o <<= 1) ss += __shfl_xor(ss, o, 64);
    if (t == 0) tau_sh = 0.9f / (sqrtf(ss) + 1e-6f);
  }
  __syncthreads();
  const float tau = tau_sh;

  // ---- M = I + tau*P (registers) ----
#pragma unroll
  for (int jj = 0; jj < 16; ++jj)
    M[jj] = tau * M[jj] + ((16 * cc + jj == ci) ? 1.0f : 0.0f);

  // ---- Gauss-Jordan inversion in registers (SPD, pivots >= 1) ----
  if (ci == 0) {
#pragma unroll
    for (int jj = 0; jj < 16; ++jj) buf2[0][16 * cc + jj] = M[jj];
  }
  __syncthreads();
#pragma unroll
  for (int k = 0; k < 64; ++k) {
    const int kb = k & 1;
    const int kc = k >> 4;   // col-slice owner of column k
    const float d = 1.0f / buf2[kb][k];
    f4 rv[4];
#pragma unroll
    for (int u = 0; u < 4; ++u) rv[u] = ld4s(&buf2[kb][16 * cc + 4 * u]);
    const float f = __shfl(M[k & 15], (l & 60) | kc, 64);  // M[i][k], pre-update
    if (ci == k) {
#pragma unroll
      for (int jj = 0; jj < 16; ++jj) M[jj] = rv[jj >> 2][jj & 3] * d;
      if (cc == kc) M[k & 15] = d;
    } else {
#pragma unroll
      for (int jj = 0; jj < 16; ++jj)
        M[jj] = fmaf(-f, rv[jj >> 2][jj & 3] * d, M[jj]);
      if (cc == kc) M[k & 15] = -f * d;
    }
    if (k < 63 && ci == k + 1) {
#pragma unroll
      for (int jj = 0; jj < 16; ++jj) buf2[1 - kb][16 * cc + jj] = M[jj];
    }
    __syncthreads();
  }

  // ---- c0 = tau * (Minv q) ----
  float c0;
  {
    float acc = 0.f;
#pragma unroll
    for (int u = 0; u < 4; ++u) {
      const f4 qv = ld4s(&q_s[16 * cc + 4 * u]);
      acc = fmaf(M[4 * u + 0], qv.x, acc);
      acc = fmaf(M[4 * u + 1], qv.y, acc);
      acc = fmaf(M[4 * u + 2], qv.z, acc);
      acc = fmaf(M[4 * u + 3], qv.w, acc);
    }
    acc += __shfl_xor(acc, 1, 64);
    acc += __shfl_xor(acc, 2, 64);
    c0 = tau * acc;
  }

  // ---- PDHG (50 iters), 3 barriers/iter, ping-pong xb2/xp2 ----
  if (t < 64) { xb2[0][t] = 0.f; xp2[0][t] = 0.f; }
  float lam = 0.f, xpr = 0.f;
  const float br = b_s[am];
  __syncthreads();

  for (int it = 0; it < 50; ++it) {
    const int p = it & 1;
    // A: lam = relu(lam - tau*(H xbar + b))   [2 lanes/row, 1 shfl]
    {
      float s = 0.f;
#pragma unroll
      for (int k = 0; k < 8; ++k) {
        const int g = 8 * as + k;
        s += dot4(ld4s(&H_s[hQ(am, g)]), ld4s(&xb2[p][4 * g]));
      }
      s += __shfl_xor(s, 1, 64);
      lam = fmaxf(lam - tau * (s + br), 0.f);
      if (as == 0) lam_s[am] = lam;
    }
    __syncthreads();
    // B: per-wave partials of H^T lam
    {
      f4 u = {0.f, 0.f, 0.f, 0.f};
#pragma unroll
      for (int k = 0; k < 8; ++k) {
        const int m = 32 * w + 8 * bc + k;
        u += ld4s(&H_s[hQ(m, bg)]) * lam_s[m];
      }
      u += shx4(u, 16); u += shx4(u, 32);
      if (l < 16) st4s(&part_s[w][4 * bg], u);
    }
    __syncthreads();
    // C: xn = Minv*(xp + tau*u) - c0   [register Minv, broadcast reads]
    {
      float acc = 0.f;
#pragma unroll
      for (int u = 0; u < 4; ++u) {
        const int j4 = 16 * cc + 4 * u;
        const f4 uv = ld4s(&part_s[0][j4]) + ld4s(&part_s[1][j4]) +
                      ld4s(&part_s[2][j4]) + ld4s(&part_s[3][j4]);
        const f4 rv = ld4s(&xp2[p][j4]) + uv * tau;
        acc = fmaf(M[4 * u + 0], rv.x, acc);
        acc = fmaf(M[4 * u + 1], rv.y, acc);
        acc = fmaf(M[4 * u + 2], rv.z, acc);
        acc = fmaf(M[4 * u + 3], rv.w, acc);
      }
      acc += __shfl_xor(acc, 1, 64);
      acc += __shfl_xor(acc, 2, 64);
      if (cc == 0) {
        const float xn = acc - c0;
        xp2[1 - p][ci] = xn;
        xb2[1 - p][ci] = 2.f * xn - xpr;
        xpr = xn;
      }
    }
    __syncthreads();
  }

  if (cc == 0) {
    const size_t oi = (size_t)blockIdx.x * NQP + ci;
    if (isf) ((float*)xs)[oi] = xpr;
    else     ((u16*)xs)[oi]   = f2b(xpr);
  }
}

// ---------------------------------------------------------------------------
extern "C" void kernel_launch(void* const* d_in, const int* in_sizes, int n_in,
                              void* d_out, int out_size, void* d_ws, size_t ws_size,
                              hipStream_t stream) {
  const void* x  = d_in[0];
  const void* W1 = d_in[1];
  const void* b1 = d_in[2];
  const void* W2 = d_in[3];
  const void* b2 = d_in[4];
  const void* W3 = d_in[5];
  const void* b3 = d_in[6];

  char* ws = (char*)d_ws;
  size_t off = 0;
  auto take = [&](size_t bytes) -> char* {
    char* r = ws + off;
    off += (bytes + 255) & ~(size_t)255;
    return r;
  };
  int*   flag = (int*)take(256);
  float* bf1  = (float*)take(1024 * 4);
  float* bf2  = (float*)take(1024 * 4);
  float* bf3  = (float*)take((size_t)NOUT * 4);
  u16*   W3t  = (u16*)take((size_t)NOUTP * 1024 * 2);
  u16*   h2hi = (u16*)take(1024ull * 1024 * 2);
  u16*   h2lo = (u16*)take(1024ull * 1024 * 2);
  char*  region = take(1024ull * NOUT * 4);   // outf, overlaid below
  float* outf = (float*)region;
  u16* xb   = (u16*)(region + 0);                 // 1 MB
  u16* W1t  = (u16*)(region + (1u << 20));        // 1 MB
  u16* W2t  = (u16*)(region + (2u << 20));        // 2 MB
  u16* h1hi = (u16*)(region + (4u << 20));        // 2 MB
  u16* h1lo = (u16*)(region + (6u << 20));        // 2 MB
  (void)ws_size; (void)in_sizes; (void)n_in; (void)out_size;

  detect_dtype<<<dim3(1), 256, 0, stream>>>((const u16*)W1, flag);

  convert_bf16<<<dim3(512), 256, 0, stream>>>(x, xb, 1024 * 512, flag);
  convert_f32<<<dim3(4), 256, 0, stream>>>(b1, bf1, 1024, flag);
  convert_f32<<<dim3(4), 256, 0, stream>>>(b2, bf2, 1024, flag);
  convert_f32<<<dim3(41), 256, 0, stream>>>(b3, bf3, NOUT, flag);

  transpose_pad<<<dim3(32, 16), 256, 0, stream>>>(W1, W1t, 512, 1024, 1024, flag);
  transpose_pad<<<dim3(32, 32), 256, 0, stream>>>(W2, W2t, 1024, 1024, 1024, flag);
  transpose_pad<<<dim3(NOUTP / 32, 32), 256, 0, stream>>>(W3, W3t, 1024, NOUT, NOUTP, flag);

  gemm_bt<0, false><<<dim3(8, 8), 256, 0, stream>>>(xb, nullptr, W1t, bf1,
                                                    h1hi, h1lo, nullptr, 1024, 1024, 512);
  gemm_bt<0, true><<<dim3(8, 8), 256, 0, stream>>>(h1hi, h1lo, W2t, bf2,
                                                   h2hi, h2lo, nullptr, 1024, 1024, 1024);
  gemm_bt<1, true><<<dim3(NOUTP / 128, 8), 256, 0, stream>>>(h2hi, h2lo, W3t, bf3,
                                                             nullptr, nullptr, outf, 1024, NOUT, 1024);
  qp_solve<<<dim3(1024), 256, 0, stream>>>(outf, d_out, flag);
}

// Round 5
// 505.487 us; speedup vs baseline: 1.6615x; 1.0271x over previous
//
#include <hip/hip_runtime.h>
#include <cstdint>

typedef unsigned short u16;
typedef __attribute__((ext_vector_type(8))) short short8;
typedef __attribute__((ext_vector_type(4))) float floatx4;
typedef __attribute__((ext_vector_type(4))) float f4;

#define NQP   64
#define MQP   128
#define NP    2080
#define NHH   8192
#define NOUT  10464   /* 2080 + 64 + 8192 + 128 */
#define NOUTP 10496   /* padded to 82*128 */

__device__ __forceinline__ float b2f(u16 u) {
  union { unsigned int i; float f; } v; v.i = ((unsigned int)u) << 16; return v.f;
}
__device__ __forceinline__ u16 f2b(float f) {
  union { float f; unsigned int i; } v; v.f = f;
  unsigned int r = v.i + 0x7fffu + ((v.i >> 16) & 1u);
  return (u16)(r >> 16);
}

// ---------------------------------------------------------------------------
// dtype detector (flag=1 -> inputs are f32)
// ---------------------------------------------------------------------------
__global__ __launch_bounds__(256) void detect_dtype(const u16* __restrict__ w,
                                                    int* __restrict__ flag) {
  __shared__ int cnt;
  if (threadIdx.x == 0) cnt = 0;
  __syncthreads();
  int c = 0;
  for (int i = threadIdx.x; i < 16384; i += 256) {
    const int e = (w[i] >> 7) & 0xFF;
    if (e >= 130 || e <= 90) ++c;
  }
  atomicAdd(&cnt, c);
  __syncthreads();
  if (threadIdx.x == 0) flag[0] = (cnt > 3000) ? 1 : 0;
}

__device__ __forceinline__ u16 load_elem_bf16(const void* p, size_t idx, int isf32) {
  return isf32 ? f2b(((const float*)p)[idx]) : ((const u16*)p)[idx];
}

__global__ __launch_bounds__(256) void convert_bf16(const void* __restrict__ in,
                                                    u16* __restrict__ out, int n,
                                                    const int* __restrict__ flag) {
  const int isf = flag[0];
  for (int i = blockIdx.x * 256 + threadIdx.x; i < n; i += gridDim.x * 256)
    out[i] = load_elem_bf16(in, i, isf);
}

// all three biases in one launch (i over 1024 + 1024 + NOUT)
__global__ __launch_bounds__(256) void conv_biases(const void* __restrict__ b1,
                                                   const void* __restrict__ b2,
                                                   const void* __restrict__ b3,
                                                   float* __restrict__ bf1,
                                                   float* __restrict__ bf2,
                                                   float* __restrict__ bf3,
                                                   const int* __restrict__ flag) {
  const int isf = flag[0];
  const int i = blockIdx.x * 256 + threadIdx.x;
  if (i < 1024) {
    bf1[i] = isf ? ((const float*)b1)[i] : b2f(((const u16*)b1)[i]);
  } else if (i < 2048) {
    const int j = i - 1024;
    bf2[j] = isf ? ((const float*)b2)[j] : b2f(((const u16*)b2)[j]);
  } else if (i < 2048 + NOUT) {
    const int j = i - 2048;
    bf3[j] = isf ? ((const float*)b3)[j] : b2f(((const u16*)b3)[j]);
  }
}

// ---------------------------------------------------------------------------
// All three weight transposes in one launch. bx ranges select W1/W2/W3.
// ---------------------------------------------------------------------------
__global__ __launch_bounds__(256) void transpose_all(const void* __restrict__ W1,
                                                     const void* __restrict__ W2,
                                                     const void* __restrict__ W3,
                                                     u16* __restrict__ W1t,
                                                     u16* __restrict__ W2t,
                                                     u16* __restrict__ W3t,
                                                     const int* __restrict__ flag) {
  const int bx = blockIdx.x, by = blockIdx.y;
  const void* in; u16* out; int K, N, Npad, bxo;
  if (bx < 32)      { in = W1; out = W1t; K = 512;  N = 1024; Npad = 1024;  bxo = 0;
                      if (by >= 16) return; }
  else if (bx < 64) { in = W2; out = W2t; K = 1024; N = 1024; Npad = 1024;  bxo = 32; }
  else              { in = W3; out = W3t; K = 1024; N = NOUT; Npad = NOUTP; bxo = 64; }
  __shared__ u16 tile[32][33];
  const int isf = flag[0];
  const int n0 = (bx - bxo) * 32, k0 = by * 32;
  const int tx = threadIdx.x & 31, ty = threadIdx.x >> 5;
#pragma unroll
  for (int i = 0; i < 4; ++i) {
    const int k = k0 + ty + 8 * i, n = n0 + tx;
    tile[ty + 8 * i][tx] = (n < N) ? load_elem_bf16(in, (size_t)k * N + n, isf) : (u16)0;
  }
  __syncthreads();
#pragma unroll
  for (int i = 0; i < 4; ++i) {
    const int n = n0 + ty + 8 * i, k = k0 + tx;
    if (n < Npad) out[(size_t)n * K + k] = tile[tx][ty + 8 * i];
  }
}

// ---------------------------------------------------------------------------
// GEMM (m97-style 128x128 tile), unchanged.
// ---------------------------------------------------------------------------
__device__ __forceinline__ void gload_lds16(const u16* g, u16* l) {
  __builtin_amdgcn_global_load_lds((const __attribute__((address_space(1))) void*)g,
                                   (__attribute__((address_space(3))) void*)l, 16, 0, 0);
}

template <int EPI, bool HAS_LO>
__global__ __launch_bounds__(256) void gemm_bt(const u16* __restrict__ Ahi, const u16* __restrict__ Alo,
                                               const u16* __restrict__ Bt,  const float* __restrict__ bias,
                                               u16* __restrict__ Chi, u16* __restrict__ Clo,
                                               float* __restrict__ Cf,
                                               int M, int N, int K) {
  __shared__ __align__(16) u16 lA[128 * 32];
  __shared__ __align__(16) u16 lAlo[128 * 32];
  __shared__ __align__(16) u16 lB[128 * 32];
  const int tile_n = blockIdx.x * 128;
  const int tile_m = blockIdx.y * 128;
  const int lane = threadIdx.x & 63;
  const int wv   = threadIdx.x >> 6;
  const int wm = (wv & 1) * 64;
  const int wn = (wv >> 1) * 64;
  const int sr = lane >> 2;
  const int sk = (lane & 3) * 8;
  floatx4 acc[4][4] = {};

  for (int k0 = 0; k0 < K; k0 += 32) {
#pragma unroll
    for (int it = 0; it < 2; ++it) {
      const int slot = it * 4 + wv;
      const int r = slot * 16 + sr;
      gload_lds16(Ahi + (size_t)(tile_m + r) * K + k0 + sk, lA + slot * 512);
      if (HAS_LO)
        gload_lds16(Alo + (size_t)(tile_m + r) * K + k0 + sk, lAlo + slot * 512);
      gload_lds16(Bt + (size_t)(tile_n + r) * K + k0 + sk, lB + slot * 512);
    }
    __syncthreads();
    const int ro = lane & 15;
    const int qo = (lane >> 4) * 8;
    short8 af[4], bfr[4], al[4];
#pragma unroll
    for (int i = 0; i < 4; ++i) af[i] = *(const short8*)(lA + (wm + i * 16 + ro) * 32 + qo);
#pragma unroll
    for (int j = 0; j < 4; ++j) bfr[j] = *(const short8*)(lB + (wn + j * 16 + ro) * 32 + qo);
    if (HAS_LO) {
#pragma unroll
      for (int i = 0; i < 4; ++i) al[i] = *(const short8*)(lAlo + (wm + i * 16 + ro) * 32 + qo);
    }
#pragma unroll
    for (int i = 0; i < 4; ++i)
#pragma unroll
      for (int j = 0; j < 4; ++j) {
        acc[i][j] = __builtin_amdgcn_mfma_f32_16x16x32_bf16(af[i], bfr[j], acc[i][j], 0, 0, 0);
        if (HAS_LO)
          acc[i][j] = __builtin_amdgcn_mfma_f32_16x16x32_bf16(al[i], bfr[j], acc[i][j], 0, 0, 0);
      }
    __syncthreads();
  }

  const int colb = tile_n + wn + (lane & 15);
  const int rowb = tile_m + wm + (lane >> 4) * 4;
#pragma unroll
  for (int j = 0; j < 4; ++j) {
    const int col = colb + j * 16;
    const float bv = (col < N) ? bias[col] : 0.f;
#pragma unroll
    for (int i = 0; i < 4; ++i) {
#pragma unroll
      for (int v = 0; v < 4; ++v) {
        const int row = rowb + i * 16 + v;
        float val = acc[i][j][v] + bv;
        if (EPI == 0) {
          val = fmaxf(val, 0.f);
          const u16 hi = f2b(val);
          const float lo = val - b2f(hi);
          Chi[(size_t)row * N + col] = hi;
          Clo[(size_t)row * N + col] = f2b(lo);
        } else {
          if (col < N) Cf[(size_t)row * N + col] = val;
        }
      }
    }
  }
}

// ---------------------------------------------------------------------------
// QP helpers
// ---------------------------------------------------------------------------
__device__ __forceinline__ f4 ld4s(const float* p) { return *(const f4*)p; }
__device__ __forceinline__ void st4s(float* p, f4 v) { *(f4*)p = v; }
__device__ __forceinline__ float dot4(f4 a, f4 b) {
  return fmaf(a.x, b.x, fmaf(a.y, b.y, fmaf(a.z, b.z, a.w * b.w)));
}
__device__ __forceinline__ f4 shx4(f4 v, int m) {
  f4 r;
  r.x = __shfl_xor(v.x, m, 64); r.y = __shfl_xor(v.y, m, 64);
  r.z = __shfl_xor(v.z, m, 64); r.w = __shfl_xor(v.w, m, 64);
  return r;
}
// XOR-swizzled float-index of f4 group g in row m (row stride 64 floats).
__device__ __forceinline__ int hQ(int m, int g) {
  return (m << 6) + (((g ^ (m & 15))) << 2);
}

// ---------------------------------------------------------------------------
// Per-batch QP solver. 1 block/batch, 256 thr, Minv in registers, 4 blk/CU.
// PDHG iter: 4 barriers — A (H xbar), B (H^T lam partials), C1 (rhs build),
// C2 (register-Minv matvec). b128/lane/iter ~28 vs round-4's ~44.
// ---------------------------------------------------------------------------
__global__ __launch_bounds__(256, 4) void qp_solve(const float* __restrict__ outbuf,
                                                   void* __restrict__ xs,
                                                   const int* __restrict__ flag) {
  __shared__ __align__(16) float H_s[8192];       // 32 KB (setup: Ld stride-68 + packed p)
  __shared__ __align__(16) float lam_s[128];      // also power-iter w staging
  __shared__ __align__(16) float b_s[128];
  __shared__ __align__(16) float part_s[4][64];
  __shared__ __align__(16) float rhs_s[64];
  __shared__ __align__(16) float xb_s[64];
  __shared__ __align__(16) float xp_s[64];
  __shared__ __align__(16) float q_s[64];
  __shared__ __align__(16) float buf2[2][64];
  __shared__ float tau_sh;

  const int t = threadIdx.x;
  const int w = t >> 6, l = t & 63;
  const int am = 32 * w + (l >> 1), as = l & 1;    // phase-A: row m, half s
  const int bg = l & 15, bc = l >> 4;              // phase-B: n-group, m-chunk
  const int ci = 16 * w + (l >> 2), cc = l & 3;    // M ownership: row i, col-slice c
  const int isf = flag[0];
  const float* ob = outbuf + (size_t)blockIdx.x * NOUT;

  // ---- setup: dense L (stride 68, zero-padded) + packed p ----
  float* Ld = H_s;                 // [0 .. 64*68) = 4352 floats
  float* ps = H_s + 4352;          // [4352 .. 6432)
  for (int e = t; e < 4352; e += 256) Ld[e] = 0.f;
  for (int e = t; e < NP; e += 256) ps[e] = ob[e];
  if (t < 64) q_s[t] = ob[NP + t];
  if (t >= 128 && t < 256) b_s[t - 128] = ob[NP + NQP + NHH + (t - 128)];
  __syncthreads();
  if (t < 64) {
    const int i = t + 1;
    const int d = i * (i + 1) / 2 - 1;
    const float xv = ps[d];
    ps[d] = 0.1f + (fmaxf(xv, 0.f) + log1pf(expf(-fabsf(xv))));
  }
  __syncthreads();
  for (int e = t; e < NP; e += 256) {
    int i = (int)((sqrtf(8.f * (float)e + 1.f) - 1.f) * 0.5f);
    while ((i + 1) * (i + 2) / 2 <= e) ++i;
    while (i * (i + 1) / 2 > e) --i;
    const int j = e - i * (i + 1) / 2;   // j <= i
    Ld[i * 68 + j] = ps[e];
  }
  __syncthreads();

  // ---- P = L L^T into registers M[16] (row ci, cols 16cc..16cc+15) ----
  float M[16];
#pragma unroll
  for (int jj = 0; jj < 16; ++jj) M[jj] = 0.f;
#pragma unroll
  for (int h = 0; h < 2; ++h) {
    f4 Lr[8];
#pragma unroll
    for (int g = 0; g < 8; ++g) Lr[g] = ld4s(&Ld[ci * 68 + (h * 8 + g) * 4]);
#pragma unroll
    for (int jj = 0; jj < 16; ++jj) {
      const int j = 16 * cc + jj;
      float s = 0.f;
#pragma unroll
      for (int g = 0; g < 8; ++g) s += dot4(Lr[g], ld4s(&Ld[j * 68 + (h * 8 + g) * 4]));
      M[jj] += s;
    }
  }
  __syncthreads();   // done with Ld/ps

  // ---- load H (swizzled f32), init power vector ----
  for (int e = t; e < NHH; e += 256) {
    const int m = e >> 6, n = e & 63;
    H_s[hQ(m, n >> 2) + (n & 3)] = ob[NP + NQP + e];
  }
  if (t < 64) xb_s[t] = 0.125f;
  __syncthreads();

  // ---- power iteration (10): v in xb_s, w staged in lam_s ----
  for (int pi = 0; pi < 10; ++pi) {
    {
      float s = 0.f;
#pragma unroll
      for (int k = 0; k < 8; ++k) {
        const int g = 8 * as + k;
        s += dot4(ld4s(&H_s[hQ(am, g)]), ld4s(&xb_s[4 * g]));
      }
      s += __shfl_xor(s, 1, 64);
      if (as == 0) lam_s[am] = s;
    }
    __syncthreads();
    {
      f4 u = {0.f, 0.f, 0.f, 0.f};
#pragma unroll
      for (int k = 0; k < 8; ++k) {
        const int m = 32 * w + 8 * bc + k;
        u += ld4s(&H_s[hQ(m, bg)]) * lam_s[m];
      }
      u += shx4(u, 16); u += shx4(u, 32);
      if (l < 16) st4s(&part_s[w][4 * bg], u);
    }
    __syncthreads();
    if (t < 64) {
      const float u = part_s[0][t] + part_s[1][t] + part_s[2][t] + part_s[3][t];
      float ss = u * u;
#pragma unroll
      for (int o = 1; o <= 32; o <<= 1) ss += __shfl_xor(ss, o, 64);
      xb_s[t] = u / (sqrtf(ss) + 1e-12f);
    }
    __syncthreads();
  }
  // ---- tau = 0.9 / (||H v|| + 1e-6) ----
  {
    float s = 0.f;
#pragma unroll
    for (int k = 0; k < 8; ++k) {
      const int g = 8 * as + k;
      s += dot4(ld4s(&H_s[hQ(am, g)]), ld4s(&xb_s[4 * g]));
    }
    s += __shfl_xor(s, 1, 64);
    if (as == 0) lam_s[am] = s;
  }
  __syncthreads();
  if (t < 64) {
    const float a = lam_s[t], bb = lam_s[t + 64];
    float ss = a * a + bb * bb;
#pragma unroll
    for (int o = 1; o <= 32; o <<= 1) ss += __shfl_xor(ss, o, 64);
    if (t == 0) tau_sh = 0.9f / (sqrtf(ss) + 1e-6f);
  }
  __syncthreads();
  const float tau = tau_sh;

  // ---- M = I + tau*P (registers) ----
#pragma unroll
  for (int jj = 0; jj < 16; ++jj)
    M[jj] = tau * M[jj] + ((16 * cc + jj == ci) ? 1.0f : 0.0f);

  // ---- Gauss-Jordan inversion in registers (SPD, pivots >= 1) ----
  if (ci == 0) {
#pragma unroll
    for (int jj = 0; jj < 16; ++jj) buf2[0][16 * cc + jj] = M[jj];
  }
  __syncthreads();
#pragma unroll
  for (int k = 0; k < 64; ++k) {
    const int kb = k & 1;
    const int kc = k >> 4;   // col-slice owner of column k
    const float d = 1.0f / buf2[kb][k];
    f4 rv[4];
#pragma unroll
    for (int u = 0; u < 4; ++u) rv[u] = ld4s(&buf2[kb][16 * cc + 4 * u]);
    const float f = __shfl(M[k & 15], (l & 60) | kc, 64);  // M[i][k], pre-update
    if (ci == k) {
#pragma unroll
      for (int jj = 0; jj < 16; ++jj) M[jj] = rv[jj >> 2][jj & 3] * d;
      if (cc == kc) M[k & 15] = d;
    } else {
#pragma unroll
      for (int jj = 0; jj < 16; ++jj)
        M[jj] = fmaf(-f, rv[jj >> 2][jj & 3] * d, M[jj]);
      if (cc == kc) M[k & 15] = -f * d;
    }
    if (k < 63 && ci == k + 1) {
#pragma unroll
      for (int jj = 0; jj < 16; ++jj) buf2[1 - kb][16 * cc + jj] = M[jj];
    }
    __syncthreads();
  }

  // ---- c0 = tau * (Minv q) ----
  float c0;
  {
    float acc = 0.f;
#pragma unroll
    for (int u = 0; u < 4; ++u) {
      const f4 qv = ld4s(&q_s[16 * cc + 4 * u]);
      acc = fmaf(M[4 * u + 0], qv.x, acc);
      acc = fmaf(M[4 * u + 1], qv.y, acc);
      acc = fmaf(M[4 * u + 2], qv.z, acc);
      acc = fmaf(M[4 * u + 3], qv.w, acc);
    }
    acc += __shfl_xor(acc, 1, 64);
    acc += __shfl_xor(acc, 2, 64);
    c0 = tau * acc;
  }

  // ---- PDHG (50 iters), 4 barriers/iter ----
  if (t < 64) { xb_s[t] = 0.f; xp_s[t] = 0.f; }
  float lam = 0.f, xpr = 0.f;
  const float br = b_s[am];
  __syncthreads();

  for (int it = 0; it < 50; ++it) {
    // A: lam = relu(lam - tau*(H xbar + b))   [2 lanes/row, 1 shfl]
    {
      float s = 0.f;
#pragma unroll
      for (int k = 0; k < 8; ++k) {
        const int g = 8 * as + k;
        s += dot4(ld4s(&H_s[hQ(am, g)]), ld4s(&xb_s[4 * g]));
      }
      s += __shfl_xor(s, 1, 64);
      lam = fmaxf(lam - tau * (s + br), 0.f);
      if (as == 0) lam_s[am] = lam;
    }
    __syncthreads();
    // B: per-wave partials of H^T lam
    {
      f4 u = {0.f, 0.f, 0.f, 0.f};
#pragma unroll
      for (int k = 0; k < 8; ++k) {
        const int m = 32 * w + 8 * bc + k;
        u += ld4s(&H_s[hQ(m, bg)]) * lam_s[m];
      }
      u += shx4(u, 16); u += shx4(u, 32);
      if (l < 16) st4s(&part_s[w][4 * bg], u);
    }
    __syncthreads();
    // C1: rhs = xp + tau * (sum of wave partials)   [64 threads]
    if (t < 64) {
      const float uu = part_s[0][t] + part_s[1][t] + part_s[2][t] + part_s[3][t];
      rhs_s[t] = xp_s[t] + tau * uu;
    }
    __syncthreads();
    // C2: xn = Minv*rhs - c0   [register Minv, broadcast rhs reads]
    {
      float acc = 0.f;
#pragma unroll
      for (int u = 0; u < 4; ++u) {
        const f4 rv = ld4s(&rhs_s[16 * cc + 4 * u]);
        acc = fmaf(M[4 * u + 0], rv.x, acc);
        acc = fmaf(M[4 * u + 1], rv.y, acc);
        acc = fmaf(M[4 * u + 2], rv.z, acc);
        acc = fmaf(M[4 * u + 3], rv.w, acc);
      }
      acc += __shfl_xor(acc, 1, 64);
      acc += __shfl_xor(acc, 2, 64);
      if (cc == 0) {
        const float xn = acc - c0;
        xp_s[ci] = xn;
        xb_s[ci] = 2.f * xn - xpr;
        xpr = xn;
      }
    }
    __syncthreads();
  }

  if (cc == 0) {
    const size_t oi = (size_t)blockIdx.x * NQP + ci;
    if (isf) ((float*)xs)[oi] = xpr;
    else     ((u16*)xs)[oi]   = f2b(xpr);
  }
}

// ---------------------------------------------------------------------------
extern "C" void kernel_launch(void* const* d_in, const int* in_sizes, int n_in,
                              void* d_out, int out_size, void* d_ws, size_t ws_size,
                              hipStream_t stream) {
  const void* x  = d_in[0];
  const void* W1 = d_in[1];
  const void* b1 = d_in[2];
  const void* W2 = d_in[3];
  const void* b2 = d_in[4];
  const void* W3 = d_in[5];
  const void* b3 = d_in[6];

  char* ws = (char*)d_ws;
  size_t off = 0;
  auto take = [&](size_t bytes) -> char* {
    char* r = ws + off;
    off += (bytes + 255) & ~(size_t)255;
    return r;
  };
  int*   flag = (int*)take(256);
  float* bf1  = (float*)take(1024 * 4);
  float* bf2  = (float*)take(1024 * 4);
  float* bf3  = (float*)take((size_t)NOUT * 4);
  u16*   W3t  = (u16*)take((size_t)NOUTP * 1024 * 2);
  u16*   h2hi = (u16*)take(1024ull * 1024 * 2);
  u16*   h2lo = (u16*)take(1024ull * 1024 * 2);
  char*  region = take(1024ull * NOUT * 4);   // outf, overlaid below
  float* outf = (float*)region;
  u16* xb   = (u16*)(region + 0);                 // 1 MB
  u16* W1t  = (u16*)(region + (1u << 20));        // 1 MB
  u16* W2t  = (u16*)(region + (2u << 20));        // 2 MB
  u16* h1hi = (u16*)(region + (4u << 20));        // 2 MB
  u16* h1lo = (u16*)(region + (6u << 20));        // 2 MB
  (void)ws_size; (void)in_sizes; (void)n_in; (void)out_size;

  detect_dtype<<<dim3(1), 256, 0, stream>>>((const u16*)W1, flag);

  convert_bf16<<<dim3(512), 256, 0, stream>>>(x, xb, 1024 * 512, flag);
  conv_biases<<<dim3(49), 256, 0, stream>>>(b1, b2, b3, bf1, bf2, bf3, flag);
  transpose_all<<<dim3(392, 32), 256, 0, stream>>>(W1, W2, W3, W1t, W2t, W3t, flag);

  gemm_bt<0, false><<<dim3(8, 8), 256, 0, stream>>>(xb, nullptr, W1t, bf1,
                                                    h1hi, h1lo, nullptr, 1024, 1024, 512);
  gemm_bt<0, true><<<dim3(8, 8), 256, 0, stream>>>(h1hi, h1lo, W2t, bf2,
                                                   h2hi, h2lo, nullptr, 1024, 1024, 1024);
  gemm_bt<1, true><<<dim3(NOUTP / 128, 8), 256, 0, stream>>>(h2hi, h2lo, W3t, bf3,
                                                             nullptr, nullptr, outf, 1024, NOUT, 1024);
  qp_solve<<<dim3(1024), 256, 0, stream>>>(outf, d_out, flag);
}